// Round 1
// baseline (476.260 us; speedup 1.0000x reference)
//
#include <hip/hip_runtime.h>
#include <hip/hip_bf16.h>

#define BB 4
#define SS 4096
#define DMODEL 512
#define DOUT 64
#define NKH 4              // split-K blocks per q-tile
#define KH (SS / NKH)      // 1024 keys per block
#define NIT (KH / 64)      // 16 iters

typedef __bf16 bf16_t;
typedef __bf16 bf16x8 __attribute__((ext_vector_type(8)));
typedef float floatx4 __attribute__((ext_vector_type(4)));

// async global->LDS, 16B per lane; HW writes lane i at ldsbase + i*16
__device__ inline void gl_lds16(const void* g, void* l) {
  __builtin_amdgcn_global_load_lds(
      (const __attribute__((address_space(1))) unsigned int*)g,
      (__attribute__((address_space(3))) unsigned int*)l, 16, 0, 0);
}

// ---------------------------------------------------------------------------
// Kernel 0: W [512][64] fp32 -> Wt [3][64][512] bf16 (transpose + cast)
// ---------------------------------------------------------------------------
__global__ __launch_bounds__(256) void wtrans_kernel(
    const float* __restrict__ Wq, const float* __restrict__ Wk,
    const float* __restrict__ Wv, bf16_t* __restrict__ wT) {
  int idx = blockIdx.x * 256 + threadIdx.x;
  int mat = idx >> 12;
  int r   = idx & 4095;
  int e   = r & 63;
  int d0  = (r >> 6) << 3;
  const float* W = (mat == 0) ? Wq : ((mat == 1) ? Wk : Wv);
  bf16_t* dst = wT + (size_t)mat * (DOUT * DMODEL) + (size_t)e * DMODEL + d0;
#pragma unroll
  for (int j = 0; j < 8; ++j) dst[j] = (bf16_t)W[(size_t)(d0 + j) * DOUT + e];
}

// ---------------------------------------------------------------------------
// Kernel 1: projections. q_ws[s][64], k_ws[s][64] bf16.
// v_wsT[b][64][4096] bf16 with KEY-SLOT PERMUTATION within each 32-key group:
// stored slot s holds key rho(s) = quad*4 + (j&3) + (j>>2)*16 (s = quad*8+j),
// so attn's PV A-fragment (packed directly from swapped-QK^T registers)
// matches V's B-fragment with plain contiguous ds_read_b128.
// ---------------------------------------------------------------------------
__global__ __launch_bounds__(256) void proj_kernel(
    const float* __restrict__ inq, const float* __restrict__ ink,
    const float* __restrict__ inv, const bf16_t* __restrict__ wT,
    const float* __restrict__ bq, const float* __restrict__ bk,
    const float* __restrict__ bv,
    bf16_t* __restrict__ q_ws, bf16_t* __restrict__ k_ws,
    bf16_t* __restrict__ v_wsT) {
  const int mat = blockIdx.x >> 8;
  const int s0  = (blockIdx.x & 255) << 6;
  const int lane = threadIdx.x & 63;
  const int w    = threadIdx.x >> 6;
  const int col  = lane & 15, quad = lane >> 4;

  const float* inp  = (mat == 0) ? inq : ((mat == 1) ? ink : inv);
  const float* bias = (mat == 0) ? bq : ((mat == 1) ? bk : bv);
  const bf16_t* wt  = wT + (size_t)mat * (DOUT * DMODEL);

  const int arow = s0 + w * 16 + col;
  const float* arow_p = inp + (size_t)arow * DMODEL;
  floatx4 acc[4] = {};

  // software-pipelined input loads (1 ch ahead)
  float4 a0 = *(const float4*)(arow_p + quad * 8);
  float4 a1 = *(const float4*)(arow_p + quad * 8 + 4);

  for (int ch = 0; ch < 16; ++ch) {
    const int chn = (ch + 1 < 16) ? ch + 1 : ch;
    float4 n0 = *(const float4*)(arow_p + chn * 32 + quad * 8);
    float4 n1 = *(const float4*)(arow_p + chn * 32 + quad * 8 + 4);

    const int d0 = ch * 32 + quad * 8;
    bf16x8 af;
    af[0] = (bf16_t)a0.x; af[1] = (bf16_t)a0.y; af[2] = (bf16_t)a0.z; af[3] = (bf16_t)a0.w;
    af[4] = (bf16_t)a1.x; af[5] = (bf16_t)a1.y; af[6] = (bf16_t)a1.z; af[7] = (bf16_t)a1.w;
#pragma unroll
    for (int c = 0; c < 4; ++c) {
      bf16x8 bw = *(const bf16x8*)(wt + (size_t)(c * 16 + col) * DMODEL + d0);
      acc[c] = __builtin_amdgcn_mfma_f32_16x16x32_bf16(af, bw, acc[c], 0, 0, 0);
    }
    a0 = n0; a1 = n1;
  }

#pragma unroll
  for (int c = 0; c < 4; ++c) {
    float bcol = bias[c * 16 + col];
#pragma unroll
    for (int r = 0; r < 4; ++r) {
      int row = s0 + w * 16 + quad * 4 + r;
      float v = acc[c][r] + bcol;
      if (mat == 2) {
        int b = row >> 12, sp = row & 4095;
        // key-slot permutation within each 32-key group (bit permutation):
        // slot bits: b0b1 = kp&3, b2 = kp>>4, b3b4 = (kp>>2)&3
        int kp = sp & 31;
        int slot = ((kp & 12) << 1) | (kp & 3) | ((kp >> 4) << 2);
        int sp2 = (sp & ~31) | slot;
        v_wsT[((size_t)(b * DOUT + c * 16 + col)) * SS + sp2] = (bf16_t)v;
      } else {
        bf16_t* dst = (mat == 0) ? q_ws : k_ws;
        dst[(size_t)row * DOUT + c * 16 + col] = (bf16_t)v;
      }
    }
  }
}

// ---------------------------------------------------------------------------
// Kernel 2: flash attention. Grid 1024 = (b, q-tile of 64) x 4 split-K
// quarters; block 256 thr = 4 waves, one 16-row q-strip each.
// SWAPPED QK^T: S^T = mfma(K,Q) puts each q-row's scores lane-local
// (lane holds P[q=col][c*16+quad*4+r]); P is packed straight into the PV
// A-fragments in registers (no LDS round-trip, no shuffles) because V's
// key columns were pre-permuted by rho^-1 in proj. One barrier per iter;
// K/V staged async double-buffered via global_load_lds; mask int4s
// register-prefetched 1 iter ahead (retired by the barrier's vmcnt(0)).
// ---------------------------------------------------------------------------
__global__ __launch_bounds__(256, 3) void attn_kernel(
    const bf16_t* __restrict__ q_ws, const bf16_t* __restrict__ k_ws,
    const bf16_t* __restrict__ v_wsT, const int* __restrict__ mask,
    float* __restrict__ O_part, float* __restrict__ l_part) {
  const int bq = blockIdx.x >> 2, kh = blockIdx.x & 3;
  const int b  = bq >> 6;
  const int q0 = (bq & 63) << 6;
  const int kbase = kh * KH;
  const int lane = threadIdx.x & 63;
  const int wi   = threadIdx.x >> 6;     // q-strip 0..3
  const int col  = lane & 15, quad = lane >> 4;

  __shared__ __align__(16) bf16_t Kb[2][64 * 64];   // [key][d], chunk-swizzled
  __shared__ __align__(16) bf16_t Vb[2][64 * 64];   // [d][slot], chunk-swizzled

  // Q fragments (serve as B-operand of swapped QK^T: B[d][q])
  const int qrowA = q0 + wi * 16 + col;
  const bf16_t* qbase = q_ws + ((size_t)(b * SS) + qrowA) * DOUT + quad * 8;
  const bf16x8 qa0 = *(const bf16x8*)(qbase);
  const bf16x8 qa1 = *(const bf16x8*)(qbase + 32);
  // mask row for q=col; 4 ints per c-block at key offset c*16 + quad*4
  const int* mrow = mask + ((size_t)(b * SS) + qrowA) * SS + quad * 4;

  // staging lane map: lane l -> row l>>3 (of 8-row group), LDS chunk l&7,
  // global chunk (l&7)^(l>>3)  => LDS(r,cp) = global(r, cp^(r&7))
  const int srow = lane >> 3;
  const int schk = (lane & 7) ^ srow;

  auto stage = [&](int it, int buf) {
    const int k0 = kbase + it * 64;
#pragma unroll
    for (int j = 0; j < 2; ++j) {
      const int i = wi * 2 + j;          // instr index 0..7 (8 rows each)
      const int r = i * 8 + srow;
      const char* gK = (const char*)(k_ws + ((size_t)(b * SS) + k0 + r) * DOUT) + schk * 16;
      gl_lds16(gK, (char*)(&Kb[buf][0]) + i * 1024);
      const char* gV = (const char*)(v_wsT + ((size_t)(b * DOUT) + r) * SS + k0) + schk * 16;
      gl_lds16(gV, (char*)(&Vb[buf][0]) + i * 1024);
    }
  };

  int4 mc[4], mn[4];
  auto loadM = [&](int k0, int4 m[4]) {
#pragma unroll
    for (int c = 0; c < 4; ++c)
      m[c] = *(const int4*)(mrow + k0 + c * 16);
  };

  floatx4 o[4] = {};
  float l_acc = 0.f;

  stage(0, 0);
  loadM(kbase, mc);
  __syncthreads();   // implies vmcnt(0): tile 0 + mask 0 complete

  for (int it = 0; it < NIT; ++it) {
    const int buf = it & 1;
    const int itn = (it + 1 < NIT) ? it + 1 : it;   // clamped restage benign

    loadM(kbase + itn * 64, mn);   // HBM prefetch; retired by next barrier
    stage(itn, buf ^ 1);           // async; retired by next barrier

    // swapped QK^T: S^T_block = K_block x Q^T  (fragments already laid out)
    floatx4 sacc[4];
#pragma unroll
    for (int c = 0; c < 4; ++c) {
      const int row = c * 16 + col;
      bf16x8 k0f = *(const bf16x8*)((const char*)&Kb[buf][0] + row * 128 + ((quad ^ (col & 7)) * 16));
      bf16x8 k1f = *(const bf16x8*)((const char*)&Kb[buf][0] + row * 128 + (((4 | quad) ^ (col & 7)) * 16));
      floatx4 z = {};
      z = __builtin_amdgcn_mfma_f32_16x16x32_bf16(k0f, qa0, z, 0, 0, 0);
      z = __builtin_amdgcn_mfma_f32_16x16x32_bf16(k1f, qa1, z, 0, 0, 0);
      sacc[c] = z;   // sacc[c][r] = S[q=col][kbase+it*64 + c*16 + quad*4 + r]
    }

    // V fragments (slot-contiguous thanks to proj's key permutation)
    bf16x8 vc[4][2];
#pragma unroll
    for (int c = 0; c < 4; ++c) {
      const int row = c * 16 + col;
      vc[c][0] = *(const bf16x8*)((const char*)&Vb[buf][0] + row * 128 + ((quad ^ (col & 7)) * 16));
      vc[c][1] = *(const bf16x8*)((const char*)&Vb[buf][0] + row * 128 + (((4 | quad) ^ (col & 7)) * 16));
    }

    // exp + mask + pack PV A-fragments fully in-register
    float lp = 0.f;
    bf16x8 pa0, pa1;
#pragma unroll
    for (int c = 0; c < 4; ++c) {
      const int4 m = mc[c];
      float p0 = (m.x != 0) ? __expf(sacc[c][0] * 0.125f) : 0.f;
      float p1 = (m.y != 0) ? __expf(sacc[c][1] * 0.125f) : 0.f;
      float p2 = (m.z != 0) ? __expf(sacc[c][2] * 0.125f) : 0.f;
      float p3 = (m.w != 0) ? __expf(sacc[c][3] * 0.125f) : 0.f;
      lp += (p0 + p1) + (p2 + p3);
      bf16x8& pa = (c < 2) ? pa0 : pa1;
      const int off = (c & 1) * 4;
      pa[off + 0] = (bf16_t)p0; pa[off + 1] = (bf16_t)p1;
      pa[off + 2] = (bf16_t)p2; pa[off + 3] = (bf16_t)p3;
    }
    lp += __shfl_xor(lp, 16);
    lp += __shfl_xor(lp, 32);
    l_acc += lp;

    // O += P V
#pragma unroll
    for (int c = 0; c < 4; ++c) {
      o[c] = __builtin_amdgcn_mfma_f32_16x16x32_bf16(pa0, vc[c][0], o[c], 0, 0, 0);
      o[c] = __builtin_amdgcn_mfma_f32_16x16x32_bf16(pa1, vc[c][1], o[c], 0, 0, 0);
    }

#pragma unroll
    for (int c = 0; c < 4; ++c) mc[c] = mn[c];

    __syncthreads();   // drains staging + mask prefetch; flips buffers
  }

  // partials out (fp32): O_part[block][64][64], l_part[block][64]
  float* Op = O_part + (size_t)blockIdx.x * 64 * 64;
#pragma unroll
  for (int c = 0; c < 4; ++c)
#pragma unroll
    for (int r = 0; r < 4; ++r)
      Op[(wi * 16 + quad * 4 + r) * 64 + c * 16 + col] = o[c][r];
  if (quad == 0) l_part[(size_t)blockIdx.x * 64 + wi * 16 + col] = l_acc;
}

// ---------------------------------------------------------------------------
// Kernel 3: combine split-K partials: out = sum(O_p) / sum(l_p)
// ---------------------------------------------------------------------------
__global__ __launch_bounds__(256) void combine_kernel(
    const float* __restrict__ O_part, const float* __restrict__ l_part,
    float* __restrict__ out) {
  const int idx = blockIdx.x * 256 + threadIdx.x;
  const int base = idx * 4;                 // element in [0, 16384*64)
  const int row = base >> 6;                // global q-row
  const int c   = base & 63;
  const int t   = row >> 6;                 // q-tile 0..255
  const int rl  = row & 63;
  float4 s = {0.f, 0.f, 0.f, 0.f};
  float lsum = 0.f;
#pragma unroll
  for (int p = 0; p < NKH; ++p) {
    const float* pp = O_part + (((size_t)(t * NKH + p) * 64 + rl) * 64 + c);
    float4 a = *(const float4*)pp;
    s.x += a.x; s.y += a.y; s.z += a.z; s.w += a.w;
    lsum += l_part[(size_t)(t * NKH + p) * 64 + rl];
  }
  const float inv = 1.0f / lsum;
  float4 r4 = {s.x * inv, s.y * inv, s.z * inv, s.w * inv};
  *(float4*)(out + base) = r4;
}

// ---------------------------------------------------------------------------
extern "C" void kernel_launch(void* const* d_in, const int* in_sizes, int n_in,
                              void* d_out, int out_size, void* d_ws, size_t ws_size,
                              hipStream_t stream) {
  const float* query = (const float*)d_in[0];
  const float* key   = (const float*)d_in[1];
  const float* value = (const float*)d_in[2];
  const int*   mask  = (const int*)d_in[3];
  const float* Wq = (const float*)d_in[4];
  const float* bq = (const float*)d_in[5];
  const float* Wk = (const float*)d_in[6];
  const float* bk = (const float*)d_in[7];
  const float* Wv = (const float*)d_in[8];
  const float* bv = (const float*)d_in[9];
  float* out = (float*)d_out;

  // ws: q_ws 2MB | k_ws 2MB | v_wsT 2MB | wT 192KB | O_part 16MB | l_part 256KB
  bf16_t* q_ws  = (bf16_t*)d_ws;
  bf16_t* k_ws  = q_ws + (size_t)BB * SS * DOUT;
  bf16_t* v_wsT = k_ws + (size_t)BB * SS * DOUT;
  bf16_t* wT    = v_wsT + (size_t)BB * SS * DOUT;
  float*  O_part = (float*)(wT + 3 * DOUT * DMODEL);
  float*  l_part = O_part + (size_t)(BB * 64 * NKH) * 64 * 64;

  hipLaunchKernelGGL(wtrans_kernel, dim3(48), dim3(256), 0, stream, Wq, Wk, Wv, wT);
  hipLaunchKernelGGL(proj_kernel, dim3(768), dim3(256), 0, stream,
                     query, key, value, wT, bq, bk, bv, q_ws, k_ws, v_wsT);
  hipLaunchKernelGGL(attn_kernel, dim3(BB * 64 * NKH), dim3(256), 0, stream,
                     q_ws, k_ws, v_wsT, mask, O_part, l_part);
  hipLaunchKernelGGL(combine_kernel, dim3(1024), dim3(256), 0, stream,
                     O_part, l_part, out);
}

// Round 2
// 475.308 us; speedup vs baseline: 1.0020x; 1.0020x over previous
//
#include <hip/hip_runtime.h>
#include <hip/hip_bf16.h>

#define BB 4
#define SS 4096
#define DMODEL 512
#define DOUT 64
#define NKH 4              // split-K blocks per q-tile
#define KH (SS / NKH)      // 1024 keys per block
#define NIT (KH / 64)      // 16 iters
#define QT 128             // q-rows per attn block (2 strips per wave)

typedef __bf16 bf16_t;
typedef __bf16 bf16x8 __attribute__((ext_vector_type(8)));
typedef float floatx4 __attribute__((ext_vector_type(4)));

// async global->LDS, 16B per lane; HW writes lane i at ldsbase + i*16
__device__ inline void gl_lds16(const void* g, void* l) {
  __builtin_amdgcn_global_load_lds(
      (const __attribute__((address_space(1))) unsigned int*)g,
      (__attribute__((address_space(3))) unsigned int*)l, 16, 0, 0);
}

// ---------------------------------------------------------------------------
// Kernel 0: W [512][64] fp32 -> Wt [3][64][512] bf16 (transpose + cast)
// ---------------------------------------------------------------------------
__global__ __launch_bounds__(256) void wtrans_kernel(
    const float* __restrict__ Wq, const float* __restrict__ Wk,
    const float* __restrict__ Wv, bf16_t* __restrict__ wT) {
  int idx = blockIdx.x * 256 + threadIdx.x;
  int mat = idx >> 12;
  int r   = idx & 4095;
  int e   = r & 63;
  int d0  = (r >> 6) << 3;
  const float* W = (mat == 0) ? Wq : ((mat == 1) ? Wk : Wv);
  bf16_t* dst = wT + (size_t)mat * (DOUT * DMODEL) + (size_t)e * DMODEL + d0;
#pragma unroll
  for (int j = 0; j < 8; ++j) dst[j] = (bf16_t)W[(size_t)(d0 + j) * DOUT + e];
}

// ---------------------------------------------------------------------------
// Kernel 1: projections. q_ws[s][64], k_ws[s][64] bf16.
// v_wsT[b][64][4096] bf16 with KEY-SLOT PERMUTATION within each 32-key group
// (slot rho^-1) so attn's register-packed PV A-fragment matches V's B-fragment
// with plain contiguous ds_read_b128.
// Both the A (input) float4 loads and the B (wT) fragment loads are
// software-pipelined 1 ch ahead to hide HBM/L2 latency under MFMA.
// ---------------------------------------------------------------------------
__global__ __launch_bounds__(256) void proj_kernel(
    const float* __restrict__ inq, const float* __restrict__ ink,
    const float* __restrict__ inv, const bf16_t* __restrict__ wT,
    const float* __restrict__ bq, const float* __restrict__ bk,
    const float* __restrict__ bv,
    bf16_t* __restrict__ q_ws, bf16_t* __restrict__ k_ws,
    bf16_t* __restrict__ v_wsT) {
  const int mat = blockIdx.x >> 8;
  const int s0  = (blockIdx.x & 255) << 6;
  const int lane = threadIdx.x & 63;
  const int w    = threadIdx.x >> 6;
  const int col  = lane & 15, quad = lane >> 4;

  const float* inp  = (mat == 0) ? inq : ((mat == 1) ? ink : inv);
  const float* bias = (mat == 0) ? bq : ((mat == 1) ? bk : bv);
  const bf16_t* wt  = wT + (size_t)mat * (DOUT * DMODEL);

  const int arow = s0 + w * 16 + col;
  const float* arow_p = inp + (size_t)arow * DMODEL;
  floatx4 acc[4] = {};

  const bf16_t* wrow[4];
#pragma unroll
  for (int c = 0; c < 4; ++c) wrow[c] = wt + (size_t)(c * 16 + col) * DMODEL;

  // software-pipelined loads (1 ch ahead): A row chunks + B fragments
  float4 a0 = *(const float4*)(arow_p + quad * 8);
  float4 a1 = *(const float4*)(arow_p + quad * 8 + 4);
  bf16x8 bwc[4], bwn[4];
#pragma unroll
  for (int c = 0; c < 4; ++c) bwc[c] = *(const bf16x8*)(wrow[c] + quad * 8);

  for (int ch = 0; ch < 16; ++ch) {
    const int chn = (ch + 1 < 16) ? ch + 1 : ch;
    const int d0n = chn * 32 + quad * 8;
    float4 n0 = *(const float4*)(arow_p + d0n);
    float4 n1 = *(const float4*)(arow_p + d0n + 4);
#pragma unroll
    for (int c = 0; c < 4; ++c) bwn[c] = *(const bf16x8*)(wrow[c] + d0n);

    bf16x8 af;
    af[0] = (bf16_t)a0.x; af[1] = (bf16_t)a0.y; af[2] = (bf16_t)a0.z; af[3] = (bf16_t)a0.w;
    af[4] = (bf16_t)a1.x; af[5] = (bf16_t)a1.y; af[6] = (bf16_t)a1.z; af[7] = (bf16_t)a1.w;
#pragma unroll
    for (int c = 0; c < 4; ++c)
      acc[c] = __builtin_amdgcn_mfma_f32_16x16x32_bf16(af, bwc[c], acc[c], 0, 0, 0);

    a0 = n0; a1 = n1;
#pragma unroll
    for (int c = 0; c < 4; ++c) bwc[c] = bwn[c];
  }

#pragma unroll
  for (int c = 0; c < 4; ++c) {
    float bcol = bias[c * 16 + col];
#pragma unroll
    for (int r = 0; r < 4; ++r) {
      int row = s0 + w * 16 + quad * 4 + r;
      float v = acc[c][r] + bcol;
      if (mat == 2) {
        int b = row >> 12, sp = row & 4095;
        // key-slot permutation within each 32-key group (bit permutation)
        int kp = sp & 31;
        int slot = ((kp & 12) << 1) | (kp & 3) | ((kp >> 4) << 2);
        int sp2 = (sp & ~31) | slot;
        v_wsT[((size_t)(b * DOUT + c * 16 + col)) * SS + sp2] = (bf16_t)v;
      } else {
        bf16_t* dst = (mat == 0) ? q_ws : k_ws;
        dst[(size_t)row * DOUT + c * 16 + col] = (bf16_t)v;
      }
    }
  }
}

// ---------------------------------------------------------------------------
// Kernel 2: flash attention. Grid 512 = (b, q-tile of 128) x 4 split-K
// quarters; block 256 thr = 4 waves, each wave owns TWO 16-row q-strips.
// K/V staged tiles and their LDS fragments are amortized over both strips:
// LDS ds_read per q-row and staging HBM/L2 traffic per q-row are HALVED vs
// the 64-row version; barrier count per q-row halves too.
// SWAPPED QK^T (S^T = mfma(K,Q)) keeps each q-row's scores lane-local; P is
// packed straight into PV A-fragments (V key columns pre-permuted in proj).
// One barrier per iter; mask int4s register-prefetched 1 iter ahead
// (retired by the barrier's vmcnt(0) -> zero-wait consume).
// ---------------------------------------------------------------------------
__global__ __launch_bounds__(256, 2) void attn_kernel(
    const bf16_t* __restrict__ q_ws, const bf16_t* __restrict__ k_ws,
    const bf16_t* __restrict__ v_wsT, const int* __restrict__ mask,
    float* __restrict__ O_part, float* __restrict__ l_part) {
  const int bq = blockIdx.x >> 2, kh = blockIdx.x & 3;
  const int b  = bq >> 5;
  const int q0 = (bq & 31) << 7;
  const int kbase = kh * KH;
  const int lane = threadIdx.x & 63;
  const int wi   = threadIdx.x >> 6;     // wave 0..3
  const int col  = lane & 15, quad = lane >> 4;

  __shared__ __align__(16) bf16_t Kb[2][64 * 64];   // [key][d], chunk-swizzled
  __shared__ __align__(16) bf16_t Vb[2][64 * 64];   // [d][slot], chunk-swizzled

  // Q fragments + mask row bases, per strip
  bf16x8 qa[2][2];
  const int* mrow[2];
#pragma unroll
  for (int s = 0; s < 2; ++s) {
    const int qrow = q0 + (wi * 2 + s) * 16 + col;
    const bf16_t* qb = q_ws + ((size_t)(b * SS) + qrow) * DOUT + quad * 8;
    qa[s][0] = *(const bf16x8*)(qb);
    qa[s][1] = *(const bf16x8*)(qb + 32);
    mrow[s] = mask + ((size_t)(b * SS) + qrow) * SS + quad * 4;
  }

  // staging lane map: lane l -> row l>>3 (of 8-row group), LDS chunk l&7,
  // global chunk (l&7)^(l>>3)  => LDS(r,cp) = global(r, cp^(r&7))
  const int srow = lane >> 3;
  const int schk = (lane & 7) ^ srow;

  auto stage = [&](int it, int buf) {
    const int k0 = kbase + it * 64;
#pragma unroll
    for (int j = 0; j < 2; ++j) {
      const int i = wi * 2 + j;          // instr index 0..7 (8 rows each)
      const int r = i * 8 + srow;
      const char* gK = (const char*)(k_ws + ((size_t)(b * SS) + k0 + r) * DOUT) + schk * 16;
      gl_lds16(gK, (char*)(&Kb[buf][0]) + i * 1024);
      const char* gV = (const char*)(v_wsT + ((size_t)(b * DOUT) + r) * SS + k0) + schk * 16;
      gl_lds16(gV, (char*)(&Vb[buf][0]) + i * 1024);
    }
  };

  int4 mc[2][4], mn[2][4];
  auto loadM = [&](int k0) {
#pragma unroll
    for (int s = 0; s < 2; ++s)
#pragma unroll
      for (int c = 0; c < 4; ++c)
        mn[s][c] = *(const int4*)(mrow[s] + k0 + c * 16);
  };

  floatx4 o[2][4] = {};
  float l_acc[2] = {0.f, 0.f};

  stage(0, 0);
  loadM(kbase);
#pragma unroll
  for (int s = 0; s < 2; ++s)
#pragma unroll
    for (int c = 0; c < 4; ++c) mc[s][c] = mn[s][c];
  __syncthreads();   // implies vmcnt(0): tile 0 + mask 0 complete

  for (int it = 0; it < NIT; ++it) {
    const int buf = it & 1;
    const int itn = (it + 1 < NIT) ? it + 1 : it;   // clamped restage benign

    loadM(kbase + itn * 64);       // HBM prefetch; retired by next barrier
    stage(itn, buf ^ 1);           // async; retired by next barrier

    // K fragments (shared by both strips)
    bf16x8 kf[4][2];
#pragma unroll
    for (int c = 0; c < 4; ++c) {
      const int row = c * 16 + col;
      kf[c][0] = *(const bf16x8*)((const char*)&Kb[buf][0] + row * 128 + ((quad ^ (col & 7)) * 16));
      kf[c][1] = *(const bf16x8*)((const char*)&Kb[buf][0] + row * 128 + (((4 | quad) ^ (col & 7)) * 16));
    }

    // swapped QK^T per strip: sacc[s][c][r] = S[q=col][k0 + c*16 + quad*4 + r]
    floatx4 sacc[2][4];
#pragma unroll
    for (int s = 0; s < 2; ++s)
#pragma unroll
      for (int c = 0; c < 4; ++c) {
        floatx4 z = {};
        z = __builtin_amdgcn_mfma_f32_16x16x32_bf16(kf[c][0], qa[s][0], z, 0, 0, 0);
        z = __builtin_amdgcn_mfma_f32_16x16x32_bf16(kf[c][1], qa[s][1], z, 0, 0, 0);
        sacc[s][c] = z;
      }

    // V fragments (shared by both strips; slot-contiguous via proj's perm)
    bf16x8 vc[4][2];
#pragma unroll
    for (int c = 0; c < 4; ++c) {
      const int row = c * 16 + col;
      vc[c][0] = *(const bf16x8*)((const char*)&Vb[buf][0] + row * 128 + ((quad ^ (col & 7)) * 16));
      vc[c][1] = *(const bf16x8*)((const char*)&Vb[buf][0] + row * 128 + (((4 | quad) ^ (col & 7)) * 16));
    }

    // exp + mask + pack PV A-fragments in-register, then PV (per strip)
#pragma unroll
    for (int s = 0; s < 2; ++s) {
      float lp = 0.f;
      bf16x8 pa0, pa1;
#pragma unroll
      for (int c = 0; c < 4; ++c) {
        const int4 m = mc[s][c];
        float p0 = (m.x != 0) ? __expf(sacc[s][c][0] * 0.125f) : 0.f;
        float p1 = (m.y != 0) ? __expf(sacc[s][c][1] * 0.125f) : 0.f;
        float p2 = (m.z != 0) ? __expf(sacc[s][c][2] * 0.125f) : 0.f;
        float p3 = (m.w != 0) ? __expf(sacc[s][c][3] * 0.125f) : 0.f;
        lp += (p0 + p1) + (p2 + p3);
        bf16x8& pa = (c < 2) ? pa0 : pa1;
        const int off = (c & 1) * 4;
        pa[off + 0] = (bf16_t)p0; pa[off + 1] = (bf16_t)p1;
        pa[off + 2] = (bf16_t)p2; pa[off + 3] = (bf16_t)p3;
      }
      lp += __shfl_xor(lp, 16);
      lp += __shfl_xor(lp, 32);
      l_acc[s] += lp;

#pragma unroll
      for (int c = 0; c < 4; ++c) {
        o[s][c] = __builtin_amdgcn_mfma_f32_16x16x32_bf16(pa0, vc[c][0], o[s][c], 0, 0, 0);
        o[s][c] = __builtin_amdgcn_mfma_f32_16x16x32_bf16(pa1, vc[c][1], o[s][c], 0, 0, 0);
      }
    }

#pragma unroll
    for (int s = 0; s < 2; ++s)
#pragma unroll
      for (int c = 0; c < 4; ++c) mc[s][c] = mn[s][c];

    __syncthreads();   // drains staging + mask prefetch; flips buffers
  }

  // partials out (fp32): O_part[block][128][64], l_part[block][128]
  float* Op = O_part + (size_t)blockIdx.x * (QT * 64);
#pragma unroll
  for (int s = 0; s < 2; ++s) {
#pragma unroll
    for (int c = 0; c < 4; ++c)
#pragma unroll
      for (int r = 0; r < 4; ++r)
        Op[((wi * 2 + s) * 16 + quad * 4 + r) * 64 + c * 16 + col] = o[s][c][r];
    if (quad == 0)
      l_part[(size_t)blockIdx.x * QT + (wi * 2 + s) * 16 + col] = l_acc[s];
  }
}

// ---------------------------------------------------------------------------
// Kernel 3: combine split-K partials: out = sum(O_p) / sum(l_p)
// ---------------------------------------------------------------------------
__global__ __launch_bounds__(256) void combine_kernel(
    const float* __restrict__ O_part, const float* __restrict__ l_part,
    float* __restrict__ out) {
  const int idx = blockIdx.x * 256 + threadIdx.x;
  const int base = idx * 4;                 // element in [0, 16384*64)
  const int row = base >> 6;                // global q-row
  const int c   = base & 63;
  const int t   = row >> 7;                 // q-tile 0..127 (128 rows each)
  const int rl  = row & 127;
  float4 s = {0.f, 0.f, 0.f, 0.f};
  float lsum = 0.f;
#pragma unroll
  for (int p = 0; p < NKH; ++p) {
    const float* pp = O_part + (((size_t)(t * NKH + p) * QT + rl) * 64 + c);
    float4 a = *(const float4*)pp;
    s.x += a.x; s.y += a.y; s.z += a.z; s.w += a.w;
    lsum += l_part[(size_t)(t * NKH + p) * QT + rl];
  }
  const float inv = 1.0f / lsum;
  float4 r4 = {s.x * inv, s.y * inv, s.z * inv, s.w * inv};
  *(float4*)(out + base) = r4;
}

// ---------------------------------------------------------------------------
extern "C" void kernel_launch(void* const* d_in, const int* in_sizes, int n_in,
                              void* d_out, int out_size, void* d_ws, size_t ws_size,
                              hipStream_t stream) {
  const float* query = (const float*)d_in[0];
  const float* key   = (const float*)d_in[1];
  const float* value = (const float*)d_in[2];
  const int*   mask  = (const int*)d_in[3];
  const float* Wq = (const float*)d_in[4];
  const float* bq = (const float*)d_in[5];
  const float* Wk = (const float*)d_in[6];
  const float* bk = (const float*)d_in[7];
  const float* Wv = (const float*)d_in[8];
  const float* bv = (const float*)d_in[9];
  float* out = (float*)d_out;

  // ws: q_ws 2MB | k_ws 2MB | v_wsT 2MB | wT 192KB | O_part 16MB | l_part 256KB
  bf16_t* q_ws  = (bf16_t*)d_ws;
  bf16_t* k_ws  = q_ws + (size_t)BB * SS * DOUT;
  bf16_t* v_wsT = k_ws + (size_t)BB * SS * DOUT;
  bf16_t* wT    = v_wsT + (size_t)BB * SS * DOUT;
  float*  O_part = (float*)(wT + 3 * DOUT * DMODEL);
  float*  l_part = O_part + (size_t)(BB * (SS / QT) * NKH) * QT * 64;

  const int attn_grid = BB * (SS / QT) * NKH;   // 512
  hipLaunchKernelGGL(wtrans_kernel, dim3(48), dim3(256), 0, stream, Wq, Wk, Wv, wT);
  hipLaunchKernelGGL(proj_kernel, dim3(768), dim3(256), 0, stream,
                     query, key, value, wT, bq, bk, bv, q_ws, k_ws, v_wsT);
  hipLaunchKernelGGL(attn_kernel, dim3(attn_grid), dim3(256), 0, stream,
                     q_ws, k_ws, v_wsT, mask, O_part, l_part);
  hipLaunchKernelGGL(combine_kernel, dim3(1024), dim3(256), 0, stream,
                     O_part, l_part, out);
}